// Round 9
// baseline (2501.200 us; speedup 1.0000x reference)
//
#include <hip/hip_runtime.h>
#include <hip/hip_bf16.h>
#include <hip/hip_fp16.h>

// Session journal (rounds 0-8):
//  r1: lgkmcnt-only barrier in k_recur -> 1965us (SLOWER). Reverted.
//  r3: 2 batches/block dot2 interleave -> VALU fully additive (710 cyc/batch-step
//      saturated) BUT exposed stall compressed 386->204/batch: stalls absorb
//      under more co-resident issue.
//  r5/r6: MFMA rewrites: 2905/2624 cyc/step vs dot2's 1096. Falsified.
//  r8: r0 config re-banked: 2336.45us total, k_recur 1884us, VALUBusy 8.08%.
//  r9 (this): TLP variant -- same batch/WG, 1024 thr = 16 waves = 4 waves/SIMD.
//  Issue per CU invariant (512 dot2-instrs/step); 4 staggered waves absorb
//  ds_read latency + barrier skew (the ~386cyc exposed stall). Fold shortens
//  to 3 DPP-adds + 2 dup-sums. Null read pre-registered: step unchanged =>
//  stall is lockstep reconvergence => structural ceiling, revert to r0.

#define DEV static __device__ __forceinline__

typedef unsigned int u32;
typedef unsigned short u16;

typedef _Float16 half2v __attribute__((ext_vector_type(2)));

union HU { u32 u; half2v h; };
union FI { float f; int i; };

#if __has_builtin(__builtin_amdgcn_fdot2)
DEV float fdot2u(u32 a, u32 b, float c){
  HU ua; ua.u = a; HU ub; ub.u = b;
  return __builtin_amdgcn_fdot2(ua.h, ub.h, c, false);
}
#else
DEV float fdot2u(u32 a, u32 b, float c){
  HU ua; ua.u = a; HU ub; ub.u = b;
  return c + (float)ua.h.x*(float)ub.h.x + (float)ua.h.y*(float)ub.h.y;
}
#endif

// cross-lane float fetch: quad_perm(0xB1=xor1, 0x4E=xor2), row_ror:8(0x128)=xor8
// (row_ror:8 within 16-lane rows == lane^8 since 8 = half of 16; r0-proven.)
#if __has_builtin(__builtin_amdgcn_mov_dpp)
DEV float dppf(float x, const int ctrl_b1, const int ctrl_4e, const int sel){
  FI u; u.f = x;
  if (sel == 0)      u.i = __builtin_amdgcn_mov_dpp(u.i, 0xB1, 0xF, 0xF, true);
  else if (sel == 1) u.i = __builtin_amdgcn_mov_dpp(u.i, 0x4E, 0xF, 0xF, true);
  else               u.i = __builtin_amdgcn_mov_dpp(u.i, 0x128, 0xF, 0xF, true);
  return u.f;
  (void)ctrl_b1; (void)ctrl_4e;
}
#define XOR1F(x) dppf((x),0,0,0)
#define XOR2F(x) dppf((x),0,0,1)
#define XOR8F(x) dppf((x),0,0,2)
#else
#define XOR1F(x) __shfl_xor((x), 1, 64)
#define XOR2F(x) __shfl_xor((x), 2, 64)
#define XOR8F(x) __shfl_xor((x), 8, 64)
#endif

#if __has_builtin(__builtin_amdgcn_ds_swizzle)
DEV float xor4f(float x){
  FI u; u.f = x;
  u.i = __builtin_amdgcn_ds_swizzle(u.i, 0x101F);  // xor-mask 4, and 0x1F
  return u.f;
}
#else
DEV float xor4f(float x){ return __shfl_xor(x, 4, 64); }
#endif

DEV u32 packh2(float x, float y){
  half2v h; h.x = (_Float16)x; h.y = (_Float16)y;
  HU u; u.h = h; return u.u;
}

DEV float bf2f(u16 v){ u32 x = ((u32)v) << 16; float f; __builtin_memcpy(&f, &x, 4); return f; }

DEV u16 f2bf(float f){
  u32 x; __builtin_memcpy(&x, &f, 4);
  u32 r = (x + 0x7fffu + ((x >> 16) & 1u)) >> 16;
  return (u16)r;
}

DEV float4 load4g(const void* p, long g, int bf){
  if (!bf) return ((const float4*)p)[g];
  ushort4 u = ((const ushort4*)p)[g];
  return make_float4(bf2f(u.x), bf2f(u.y), bf2f(u.z), bf2f(u.w));
}
DEV float load1g(const void* p, long i, int bf){
  return bf ? bf2f(((const u16*)p)[i]) : ((const float*)p)[i];
}

// ---------------- K_detect: decide f32 vs bf16 inputs ----------------
__global__ void k_detect(const void* __restrict__ A, int* __restrict__ flag){
  float a0 = ((const float*)A)[0];
  *flag = !(a0 > 0.5f && a0 < 2.0f);
}

// ---------------- K0: B = A^T A (fp32, 256x256) ----------------
__global__ __launch_bounds__(256) void k_btb(const void* __restrict__ A, float* __restrict__ Bm,
                                             const int* __restrict__ flag){
  __shared__ float acol[256];
  int t = threadIdx.x, r = blockIdx.x, bf = *flag;
  acol[t] = load1g(A, (long)t*256 + r, bf);
  __syncthreads();
  float acc = 0.f;
  if (bf){
    const u16* Ab = (const u16*)A;
    #pragma unroll 4
    for (int k = 0; k < 256; k++) acc += acol[k] * bf2f(Ab[(long)k*256 + t]);
  } else {
    const float* Af = (const float*)A;
    #pragma unroll 4
    for (int k = 0; k < 256; k++) acc += acol[k] * Af[(long)k*256 + t];
  }
  Bm[(long)r*256 + t] = acc;
}

// ---------------- K1: Lanczos (no reorth, 40 it) + 64-lane multisection Sturm ----------------
__global__ __launch_bounds__(512) void k_lanczos(const float* __restrict__ Bm, float* __restrict__ out_scale){
  const int NIT = 40;
  __shared__ float vbuf[256], vprev[256];
  __shared__ float part[2][256];
  __shared__ float red[8];
  __shared__ float al[NIT], be[NIT + 1];
  int tid = threadIdx.x;
  int i = tid & 255, kh = tid >> 8;

  float4 Breg[32];
  #pragma unroll
  for (int g = 0; g < 32; g++) Breg[g] = ((const float4*)Bm)[(long)i*64 + kh*32 + g];

  if (tid == 0) be[0] = 0.f;
  if (tid < 256){
    u32 rs = (u32)tid*1103515245u + 12345u;
    rs ^= rs >> 13; rs *= 2654435761u; rs ^= rs >> 16;
    vbuf[tid] = (float)(rs & 0xffffu)/32768.0f - 1.0f;
    vprev[tid] = 0.f;
  }
  __syncthreads();
  if (tid < 256){
    float p = vbuf[tid]*vbuf[tid];
    #pragma unroll
    for (int m = 1; m < 64; m <<= 1) p += __shfl_xor(p, m, 64);
    if ((tid & 63) == 0) red[tid >> 6] = p;
  }
  __syncthreads();
  {
    float nv = rsqrtf(red[0]+red[1]+red[2]+red[3]);
    if (tid < 256) vbuf[tid] *= nv;
  }
  __syncthreads();

  float bprev = 0.f;
  for (int it = 0; it < NIT; it++){
    const float4* vb4 = (const float4*)vbuf;
    float4 acc = {0.f,0.f,0.f,0.f};
    #pragma unroll
    for (int g = 0; g < 32; g++){
      float4 bq = Breg[g]; float4 v = vb4[kh*32 + g];
      acc.x += bq.x*v.x; acc.y += bq.y*v.y; acc.z += bq.z*v.z; acc.w += bq.w*v.w;
    }
    part[kh][i] = acc.x+acc.y+acc.z+acc.w;
    __syncthreads();                               // B1
    float w = 0.f;
    if (tid < 256){
      w = part[0][tid] + part[1][tid];
      float p = w * vbuf[tid];
      #pragma unroll
      for (int m = 1; m < 64; m <<= 1) p += __shfl_xor(p, m, 64);
      if ((tid & 63) == 0) red[tid >> 6] = p;
    }
    __syncthreads();                               // B2
    float alpha = red[0]+red[1]+red[2]+red[3];
    if (tid == 0) al[it] = alpha;
    __syncthreads();                               // B3 (red consumed before reuse)
    if (tid < 256){
      w -= alpha*vbuf[tid] + bprev*vprev[tid];
      float p = w*w;
      #pragma unroll
      for (int m = 1; m < 64; m <<= 1) p += __shfl_xor(p, m, 64);
      if ((tid & 63) == 0) red[tid >> 6] = p;
    }
    __syncthreads();                               // B4
    float bnew = sqrtf(fmaxf(red[0]+red[1]+red[2]+red[3], 0.f));
    if (tid == 0) be[it+1] = bnew;
    if (tid < 256){
      vprev[tid] = vbuf[tid];
      vbuf[tid] = (bnew > 1e-12f) ? (w / bnew) : 0.f;
    }
    bprev = bnew;
    __syncthreads();                               // B5
  }

  if (tid < 64){
    float amax = -1e30f, gmax = -1e30f;
    for (int q = 0; q < NIT; q++){
      float b0 = (q > 0)       ? be[q]   : 0.f;
      float b1 = (q < NIT-1)   ? be[q+1] : 0.f;
      gmax = fmaxf(gmax, al[q] + fabsf(b0) + fabsf(b1));
      amax = fmaxf(amax, al[q]);
    }
    float lo = amax - 1e-4f, hi = gmax + 1e-3f;
    for (int r = 0; r < 4; r++){
      float step = (hi - lo) * (1.0f/65.0f);
      float cand = lo + step * (float)(tid + 1);
      int cnt = 0;
      float dd = al[0] - cand;
      if (dd < 0.f) cnt++;
      for (int q = 1; q < NIT; q++){
        float bq = be[q];
        if (fabsf(dd) < 1e-25f) dd = -1e-25f;
        dd = (al[q] - cand) - bq*bq/dd;
        if (dd < 0.f) cnt++;
      }
      unsigned long long mask = __ballot(cnt >= NIT);
      if (mask == 0ull){
        lo = lo + step*64.f;
      } else {
        int bb = __ffsll((long long)mask) - 1;
        float nlo = lo + step*(float)bb;
        float nhi = lo + step*(float)(bb+1);
        lo = nlo; hi = nhi;
      }
    }
    if (tid == 0){
      float lam = fmaxf(0.5f*(lo + hi), 1e-12f);
      *out_scale = 1.0f/(sqrtf(lam) + 1e-5f);
    }
  }
}

// ---------------- K2: u = x @ W_B^T  (f16 pairs into scratch) ----------------
__global__ __launch_bounds__(256) void k_uproj(const void* __restrict__ x, const void* __restrict__ WB,
                                               u32* __restrict__ scr, const int* __restrict__ flag){
  __shared__ alignas(16) u32 Wt[64*260];
  __shared__ alignas(16) u32 xt[64*36];
  int tid = threadIdx.x;
  int bf = *flag;
  long T0 = (long)blockIdx.x * 32;
  #pragma unroll
  for (int i2 = 0; i2 < 32; i2++){
    int f = tid + 256*i2;
    int cq = f & 31, h = f >> 5;
    float4 v = load4g(WB, (long)h*32 + cq, bf);
    Wt[(2*cq)*260 + h]   = packh2(v.x, v.y);
    Wt[(2*cq+1)*260 + h] = packh2(v.z, v.w);
  }
  #pragma unroll
  for (int i2 = 0; i2 < 4; i2++){
    int f = tid + 256*i2;
    int cq = f & 31, t = f >> 5;
    float4 v = load4g(x, (T0 + t)*32 + cq, bf);
    xt[(2*cq)*36 + t]   = packh2(v.x, v.y);
    xt[(2*cq+1)*36 + t] = packh2(v.z, v.w);
  }
  __syncthreads();
  int hg = tid & 63, tg = tid >> 6;
  float acc[4][8];
  #pragma unroll
  for (int a1 = 0; a1 < 4; a1++)
    for (int b1 = 0; b1 < 8; b1++) acc[a1][b1] = 0.f;
  #pragma unroll 4
  for (int kp = 0; kp < 64; kp++){
    uint4 wv = *(const uint4*)&Wt[kp*260 + 4*hg];
    uint4 xa = *(const uint4*)&xt[kp*36 + 8*tg];
    uint4 xb = *(const uint4*)&xt[kp*36 + 8*tg + 4];
    u32 wj[4] = {wv.x, wv.y, wv.z, wv.w};
    u32 xs[8] = {xa.x, xa.y, xa.z, xa.w, xb.x, xb.y, xb.z, xb.w};
    #pragma unroll
    for (int jj = 0; jj < 4; jj++)
      #pragma unroll
      for (int tt = 0; tt < 8; tt++)
        acc[jj][tt] = fdot2u(wj[jj], xs[tt], acc[jj][tt]);
  }
  #pragma unroll
  for (int tt = 0; tt < 8; tt++){
    long T = T0 + 8*tg + tt;
    uint2 o;
    o.x = packh2(acc[0][tt], acc[1][tt]);
    o.y = packh2(acc[2][tt], acc[3][tt]);
    ((uint2*)scr)[T*64 + hg] = o;
  }
}

// ---------------- K3: recurrence, TLP variant. 1024 thr = 16 waves = 4 waves/SIMD.
// thread (i=tid>>4 in 0..63, j=tid&15) owns rows 4i..4i+3 via slot s in 0..3:
// R = 4i + ((j^s)&3). Per thread: 4 slots x 16 cols = 32 fdot2 (same total issue
// per CU as r0's 8x64; TLP doubled to absorb the ~386cyc exposed stall, per r3's
// measured stall compression 386->204 under doubled co-resident issue).
// Fold: xor1 pairs (0,1),(2,3); xor2 pair (0,2) -> acc0 = row (j&3) over 64 cols;
// dup-sums over j^4 (swizzle) and j^8 (DPP ror:8) -> full 256-col sum on all
// 4 dup lanes. All dup writes idempotent. Refill/prologue gated tid<512
// (wave-uniform: waves 0-7).
__global__ __launch_bounds__(1024, 4) void k_recur(const void* __restrict__ A, const float* __restrict__ scale_p,
                                                   u32* __restrict__ scr, const int* __restrict__ flag){
  __shared__ alignas(16) char hbuf[2][768];
  __shared__ alignas(16) __half uring[32*256];    // 16 KB, 2 slots x 16 steps
  int tid = threadIdx.x;
  int i = tid >> 4, j = tid & 15;
  int b = blockIdx.x;
  int bf = *flag;
  float s = *scale_p;
  int myrow = 4*i + (j & 3);

  u32 a[4][8];
  #pragma unroll
  for (int sx = 0; sx < 4; sx++){
    int R = 4*i + ((j ^ sx) & 3);
    #pragma unroll
    for (int q = 0; q < 4; q++){
      float4 v = load4g(A, (long)R*64 + 4*j + q, bf);
      float vv[4] = {v.x, v.y, v.z, v.w};
      #pragma unroll
      for (int e = 0; e < 4; e++){
        int col = 16*j + 4*q + e;
        if (col == R) vv[e] = 0.f;
      }
      a[sx][2*q]   = packh2(vv[0]*s, vv[1]*s);
      a[sx][2*q+1] = packh2(vv[2]*s, vv[3]*s);
    }
  }
  float d = load1g(A, (long)myrow*257, bf) * s;   // diagonal of my final row, fp32

  const uint4* scr4 = (const uint4*)scr;
  uint4* ur4 = (uint4*)uring;
  long ubase4 = (long)b * 131072;                  // uint4 idx of u[b][0]
  u16* hsout = (u16*)scr + (long)b*4096*256;

  uint4 pf = make_uint4(0, 0, 0, 0);
  if (tid < 512){
    ur4[tid] = scr4[ubase4 + tid];                 // chunk 0 -> slot 0
    pf = scr4[ubase4 + 512 + tid];                 // chunk 1 -> regs
  }

  int hoff16 = 24*(myrow >> 4) + (myrow & 15);     // u16 idx: 48B block stride
  ((u16*)hbuf[0])[hoff16] = 0;                     // dups write same value
  ((u16*)hbuf[1])[hoff16] = 0;
  __syncthreads();

  float hprev = 0.f;
  #pragma unroll 1
  for (int t = 0; t < 4096; ++t){
    const uint4* h4 = (const uint4*)(hbuf[t & 1] + 48*j);
    uint4 h0 = h4[0], h1 = h4[1];
    float uv = __half2float(uring[(t & 31)*256 + myrow]);
    float acc[4];
    #pragma unroll
    for (int sx = 0; sx < 4; sx++){
      float ac = 0.f;
      ac = fdot2u(a[sx][0], h0.x, ac);
      ac = fdot2u(a[sx][1], h0.y, ac);
      ac = fdot2u(a[sx][2], h0.z, ac);
      ac = fdot2u(a[sx][3], h0.w, ac);
      ac = fdot2u(a[sx][4], h1.x, ac);
      ac = fdot2u(a[sx][5], h1.y, ac);
      ac = fdot2u(a[sx][6], h1.z, ac);
      ac = fdot2u(a[sx][7], h1.w, ac);
      acc[sx] = ac;
    }
    // fold bit0 (xor1) over slot pairs, bit1 (xor2); then dup-sum over j^4, j^8
    acc[0] += XOR1F(acc[1]);
    acc[2] += XOR1F(acc[3]);
    acc[0] += XOR2F(acc[2]);
    float s1 = acc[0] + xor4f(acc[0]);
    float sum = s1 + XOR8F(s1);

    float hnew = fmaxf(fmaf(d, hprev, sum + uv), 0.f);
    hprev = hnew;
    u16 hh = __half_as_ushort(__float2half(hnew));
    ((u16*)hbuf[(t & 1) ^ 1])[hoff16] = hh;        // 4 dup lanes write same value
    hsout[(long)t*256 + myrow] = hh;               // 4 dup lanes write same value

    if ((t & 15) == 15 && t < 4095){
      if (tid < 512){                              // wave-uniform gate (waves 0-7)
        int ct = (t + 1) >> 4;
        ur4[(ct & 1)*512 + tid] = pf;
        if (ct < 255) pf = scr4[ubase4 + (long)(ct + 1)*512 + tid];
      }
    }
    __syncthreads();
  }
}

// ---------------- K4: y = hs @ W_C^T ----------------
__global__ __launch_bounds__(256) void k_yproj(const u32* __restrict__ scr, const void* __restrict__ WC,
                                               void* __restrict__ y, const int* __restrict__ flag){
  __shared__ alignas(16) u32 Wt[128*132];
  __shared__ alignas(16) u32 ht[128*68];
  int tid = threadIdx.x, bf = *flag;
  long T0 = (long)blockIdx.x * 64;
  #pragma unroll
  for (int i2 = 0; i2 < 32; i2++){
    int f = tid + 256*i2;
    int kp = f & 127, t = f >> 7;
    ht[kp*68 + t] = scr[(T0 + t)*128 + kp];
  }
  #pragma unroll
  for (int i2 = 0; i2 < 32; i2++){
    int f = tid + 256*i2;
    int kq = f & 63, o = f >> 6;
    float4 v = load4g(WC, (long)o*64 + kq, bf);
    Wt[(2*kq)*132 + o]   = packh2(v.x, v.y);
    Wt[(2*kq+1)*132 + o] = packh2(v.z, v.w);
  }
  __syncthreads();
  int og = tid & 31, tg = tid >> 5;
  float acc[4][8];
  #pragma unroll
  for (int a1 = 0; a1 < 4; a1++)
    for (int b1 = 0; b1 < 8; b1++) acc[a1][b1] = 0.f;
  #pragma unroll 4
  for (int kp = 0; kp < 128; kp++){
    uint4 wv = *(const uint4*)&Wt[kp*132 + 4*og];
    uint4 ha = *(const uint4*)&ht[kp*68 + 8*tg];
    uint4 hc = *(const uint4*)&ht[kp*68 + 8*tg + 4];
    u32 wj[4] = {wv.x, wv.y, wv.z, wv.w};
    u32 hs8[8] = {ha.x, ha.y, ha.z, ha.w, hc.x, hc.y, hc.z, hc.w};
    #pragma unroll
    for (int jj = 0; jj < 4; jj++)
      #pragma unroll
      for (int tt = 0; tt < 8; tt++)
        acc[jj][tt] = fdot2u(wj[jj], hs8[tt], acc[jj][tt]);
  }
  #pragma unroll
  for (int tt = 0; tt < 8; tt++){
    long T = T0 + 8*tg + tt;
    if (!bf){
      float4 o = {acc[0][tt], acc[1][tt], acc[2][tt], acc[3][tt]};
      ((float4*)y)[T*32 + og] = o;
    } else {
      uint2 o;
      o.x = (u32)f2bf(acc[0][tt]) | ((u32)f2bf(acc[1][tt]) << 16);
      o.y = (u32)f2bf(acc[2][tt]) | ((u32)f2bf(acc[3][tt]) << 16);
      ((uint2*)y)[T*32 + og] = o;
    }
  }
}

extern "C" void kernel_launch(void* const* d_in, const int* in_sizes, int n_in,
                              void* d_out, int out_size, void* d_ws, size_t ws_size,
                              hipStream_t stream){
  const void* x  = d_in[0];
  const void* A  = d_in[1];
  const void* WB = d_in[2];
  const void* WC = d_in[3];

  float* Bm    = (float*)d_ws;
  float* scale = (float*)((char*)d_ws + 256*1024);
  int*   flag  = (int*)((char*)d_ws + 256*1024 + 64);

  const size_t scrOff = (size_t)1 << 20;
  const size_t scrBytes = (size_t)131072 * 256 * 2;   // 64 MiB of f16
  u32* scr = (ws_size >= scrOff + scrBytes + 4096)
               ? (u32*)((char*)d_ws + scrOff)
               : (u32*)d_out;

  k_detect <<<1, 1, 0, stream>>>(A, flag);
  k_btb    <<<256, 256, 0, stream>>>(A, Bm, flag);
  k_lanczos<<<1, 512, 0, stream>>>(Bm, scale);
  k_uproj  <<<4096, 256, 0, stream>>>(x, WB, scr, flag);
  k_recur  <<<32, 1024, 0, stream>>>(A, scale, scr, flag);
  k_yproj  <<<2048, 256, 0, stream>>>(scr, WC, d_out, flag);
}

// Round 10
// 2328.250 us; speedup vs baseline: 1.0743x; 1.0743x over previous
//
#include <hip/hip_runtime.h>
#include <hip/hip_bf16.h>
#include <hip/hip_fp16.h>

// Session journal (rounds 0-9) -- FINAL STATE, measured optimum (2336.45 us):
//  r1: lgkmcnt-only barrier in k_recur -> 1965us (SLOWER). Reverted.
//  r3: 2 batches/block dot2 interleave -> VALU fully additive (710 cyc/batch-step
//      saturated): k_recur is VALU-issue-bound, not latency-bound.
//  r5/r6: MFMA rewrites (frag maps HW-verified by passing absmax): 2905/2624
//      cyc/step vs dot2's 1096. Matrix-pipe direction falsified for this shape.
//  r9: TLP variant (1024 thr, 4 waves/SIMD, same issue): step 1096->1203 cyc.
//      Lockstep barrier reconvergence is not absorbable by co-residency; extra
//      threads double the constant per-thread overhead issue. Falsified.
//  Ceiling argument: 4096 serial steps x ~1096 cyc (710 saturated VALU issue +
//  ~390 lockstep reconvergence) on 1 CU/batch; all three orthogonal levers
//  (barrier semantics, matrix pipe, issue/latency overlap) measured negative.

#define DEV static __device__ __forceinline__

typedef unsigned int u32;
typedef unsigned short u16;

typedef _Float16 half2v __attribute__((ext_vector_type(2)));

union HU { u32 u; half2v h; };
union FI { float f; int i; };

#if __has_builtin(__builtin_amdgcn_fdot2)
DEV float fdot2u(u32 a, u32 b, float c){
  HU ua; ua.u = a; HU ub; ub.u = b;
  return __builtin_amdgcn_fdot2(ua.h, ub.h, c, false);
}
#else
DEV float fdot2u(u32 a, u32 b, float c){
  HU ua; ua.u = a; HU ub; ub.u = b;
  return c + (float)ua.h.x*(float)ub.h.x + (float)ua.h.y*(float)ub.h.y;
}
#endif

// cross-lane float fetch: quad_perm(0xB1=xor1, 0x4E=xor2), row_ror:8(0x128)=xor8
#if __has_builtin(__builtin_amdgcn_mov_dpp)
DEV float dppf(float x, const int ctrl_b1, const int ctrl_4e, const int sel){
  FI u; u.f = x;
  if (sel == 0)      u.i = __builtin_amdgcn_mov_dpp(u.i, 0xB1, 0xF, 0xF, true);
  else if (sel == 1) u.i = __builtin_amdgcn_mov_dpp(u.i, 0x4E, 0xF, 0xF, true);
  else               u.i = __builtin_amdgcn_mov_dpp(u.i, 0x128, 0xF, 0xF, true);
  return u.f;
  (void)ctrl_b1; (void)ctrl_4e;
}
#define XOR1F(x) dppf((x),0,0,0)
#define XOR2F(x) dppf((x),0,0,1)
#define XOR8F(x) dppf((x),0,0,2)
#else
#define XOR1F(x) __shfl_xor((x), 1, 64)
#define XOR2F(x) __shfl_xor((x), 2, 64)
#define XOR8F(x) __shfl_xor((x), 8, 64)
#endif

#if __has_builtin(__builtin_amdgcn_ds_swizzle)
DEV float xor4f(float x){
  FI u; u.f = x;
  u.i = __builtin_amdgcn_ds_swizzle(u.i, 0x101F);  // xor-mask 4, and 0x1F
  return u.f;
}
#else
DEV float xor4f(float x){ return __shfl_xor(x, 4, 64); }
#endif

DEV u32 packh2(float x, float y){
  half2v h; h.x = (_Float16)x; h.y = (_Float16)y;
  HU u; u.h = h; return u.u;
}

DEV float bf2f(u16 v){ u32 x = ((u32)v) << 16; float f; __builtin_memcpy(&f, &x, 4); return f; }

DEV u16 f2bf(float f){
  u32 x; __builtin_memcpy(&x, &f, 4);
  u32 r = (x + 0x7fffu + ((x >> 16) & 1u)) >> 16;
  return (u16)r;
}

DEV float4 load4g(const void* p, long g, int bf){
  if (!bf) return ((const float4*)p)[g];
  ushort4 u = ((const ushort4*)p)[g];
  return make_float4(bf2f(u.x), bf2f(u.y), bf2f(u.z), bf2f(u.w));
}
DEV float load1g(const void* p, long i, int bf){
  return bf ? bf2f(((const u16*)p)[i]) : ((const float*)p)[i];
}

// final-row map: lane j owns local row m(j) = bits{0,1,3} of j
DEV int mloc(int v){ return (v & 3) | ((v & 8) >> 1); }

// ---------------- K_detect: decide f32 vs bf16 inputs ----------------
__global__ void k_detect(const void* __restrict__ A, int* __restrict__ flag){
  float a0 = ((const float*)A)[0];
  *flag = !(a0 > 0.5f && a0 < 2.0f);
}

// ---------------- K0: B = A^T A (fp32, 256x256) ----------------
__global__ __launch_bounds__(256) void k_btb(const void* __restrict__ A, float* __restrict__ Bm,
                                             const int* __restrict__ flag){
  __shared__ float acol[256];
  int t = threadIdx.x, r = blockIdx.x, bf = *flag;
  acol[t] = load1g(A, (long)t*256 + r, bf);
  __syncthreads();
  float acc = 0.f;
  if (bf){
    const u16* Ab = (const u16*)A;
    #pragma unroll 4
    for (int k = 0; k < 256; k++) acc += acol[k] * bf2f(Ab[(long)k*256 + t]);
  } else {
    const float* Af = (const float*)A;
    #pragma unroll 4
    for (int k = 0; k < 256; k++) acc += acol[k] * Af[(long)k*256 + t];
  }
  Bm[(long)r*256 + t] = acc;
}

// ---------------- K1: Lanczos (no reorth, 40 it) + 64-lane multisection Sturm ----------------
__global__ __launch_bounds__(512) void k_lanczos(const float* __restrict__ Bm, float* __restrict__ out_scale){
  const int NIT = 40;
  __shared__ float vbuf[256], vprev[256];
  __shared__ float part[2][256];
  __shared__ float red[8];
  __shared__ float al[NIT], be[NIT + 1];
  int tid = threadIdx.x;
  int i = tid & 255, kh = tid >> 8;

  float4 Breg[32];
  #pragma unroll
  for (int g = 0; g < 32; g++) Breg[g] = ((const float4*)Bm)[(long)i*64 + kh*32 + g];

  if (tid == 0) be[0] = 0.f;
  if (tid < 256){
    u32 rs = (u32)tid*1103515245u + 12345u;
    rs ^= rs >> 13; rs *= 2654435761u; rs ^= rs >> 16;
    vbuf[tid] = (float)(rs & 0xffffu)/32768.0f - 1.0f;
    vprev[tid] = 0.f;
  }
  __syncthreads();
  if (tid < 256){
    float p = vbuf[tid]*vbuf[tid];
    #pragma unroll
    for (int m = 1; m < 64; m <<= 1) p += __shfl_xor(p, m, 64);
    if ((tid & 63) == 0) red[tid >> 6] = p;
  }
  __syncthreads();
  {
    float nv = rsqrtf(red[0]+red[1]+red[2]+red[3]);
    if (tid < 256) vbuf[tid] *= nv;
  }
  __syncthreads();

  float bprev = 0.f;
  for (int it = 0; it < NIT; it++){
    const float4* vb4 = (const float4*)vbuf;
    float4 acc = {0.f,0.f,0.f,0.f};
    #pragma unroll
    for (int g = 0; g < 32; g++){
      float4 bq = Breg[g]; float4 v = vb4[kh*32 + g];
      acc.x += bq.x*v.x; acc.y += bq.y*v.y; acc.z += bq.z*v.z; acc.w += bq.w*v.w;
    }
    part[kh][i] = acc.x+acc.y+acc.z+acc.w;
    __syncthreads();                               // B1
    float w = 0.f;
    if (tid < 256){
      w = part[0][tid] + part[1][tid];
      float p = w * vbuf[tid];
      #pragma unroll
      for (int m = 1; m < 64; m <<= 1) p += __shfl_xor(p, m, 64);
      if ((tid & 63) == 0) red[tid >> 6] = p;
    }
    __syncthreads();                               // B2
    float alpha = red[0]+red[1]+red[2]+red[3];
    if (tid == 0) al[it] = alpha;
    __syncthreads();                               // B3 (red consumed before reuse)
    if (tid < 256){
      w -= alpha*vbuf[tid] + bprev*vprev[tid];
      float p = w*w;
      #pragma unroll
      for (int m = 1; m < 64; m <<= 1) p += __shfl_xor(p, m, 64);
      if ((tid & 63) == 0) red[tid >> 6] = p;
    }
    __syncthreads();                               // B4
    float bnew = sqrtf(fmaxf(red[0]+red[1]+red[2]+red[3], 0.f));
    if (tid == 0) be[it+1] = bnew;
    if (tid < 256){
      vprev[tid] = vbuf[tid];
      vbuf[tid] = (bnew > 1e-12f) ? (w / bnew) : 0.f;
    }
    bprev = bnew;
    __syncthreads();                               // B5
  }

  if (tid < 64){
    float amax = -1e30f, gmax = -1e30f;
    for (int q = 0; q < NIT; q++){
      float b0 = (q > 0)       ? be[q]   : 0.f;
      float b1 = (q < NIT-1)   ? be[q+1] : 0.f;
      gmax = fmaxf(gmax, al[q] + fabsf(b0) + fabsf(b1));
      amax = fmaxf(amax, al[q]);
    }
    float lo = amax - 1e-4f, hi = gmax + 1e-3f;
    for (int r = 0; r < 4; r++){
      float step = (hi - lo) * (1.0f/65.0f);
      float cand = lo + step * (float)(tid + 1);
      int cnt = 0;
      float dd = al[0] - cand;
      if (dd < 0.f) cnt++;
      for (int q = 1; q < NIT; q++){
        float bq = be[q];
        if (fabsf(dd) < 1e-25f) dd = -1e-25f;
        dd = (al[q] - cand) - bq*bq/dd;
        if (dd < 0.f) cnt++;
      }
      unsigned long long mask = __ballot(cnt >= NIT);
      if (mask == 0ull){
        lo = lo + step*64.f;
      } else {
        int bb = __ffsll((long long)mask) - 1;
        float nlo = lo + step*(float)bb;
        float nhi = lo + step*(float)(bb+1);
        lo = nlo; hi = nhi;
      }
    }
    if (tid == 0){
      float lam = fmaxf(0.5f*(lo + hi), 1e-12f);
      *out_scale = 1.0f/(sqrtf(lam) + 1e-5f);
    }
  }
}

// ---------------- K2: u = x @ W_B^T  (f16 pairs into scratch) ----------------
__global__ __launch_bounds__(256) void k_uproj(const void* __restrict__ x, const void* __restrict__ WB,
                                               u32* __restrict__ scr, const int* __restrict__ flag){
  __shared__ alignas(16) u32 Wt[64*260];
  __shared__ alignas(16) u32 xt[64*36];
  int tid = threadIdx.x;
  int bf = *flag;
  long T0 = (long)blockIdx.x * 32;
  #pragma unroll
  for (int i2 = 0; i2 < 32; i2++){
    int f = tid + 256*i2;
    int cq = f & 31, h = f >> 5;
    float4 v = load4g(WB, (long)h*32 + cq, bf);
    Wt[(2*cq)*260 + h]   = packh2(v.x, v.y);
    Wt[(2*cq+1)*260 + h] = packh2(v.z, v.w);
  }
  #pragma unroll
  for (int i2 = 0; i2 < 4; i2++){
    int f = tid + 256*i2;
    int cq = f & 31, t = f >> 5;
    float4 v = load4g(x, (T0 + t)*32 + cq, bf);
    xt[(2*cq)*36 + t]   = packh2(v.x, v.y);
    xt[(2*cq+1)*36 + t] = packh2(v.z, v.w);
  }
  __syncthreads();
  int hg = tid & 63, tg = tid >> 6;
  float acc[4][8];
  #pragma unroll
  for (int a1 = 0; a1 < 4; a1++)
    for (int b1 = 0; b1 < 8; b1++) acc[a1][b1] = 0.f;
  #pragma unroll 4
  for (int kp = 0; kp < 64; kp++){
    uint4 wv = *(const uint4*)&Wt[kp*260 + 4*hg];
    uint4 xa = *(const uint4*)&xt[kp*36 + 8*tg];
    uint4 xb = *(const uint4*)&xt[kp*36 + 8*tg + 4];
    u32 wj[4] = {wv.x, wv.y, wv.z, wv.w};
    u32 xs[8] = {xa.x, xa.y, xa.z, xa.w, xb.x, xb.y, xb.z, xb.w};
    #pragma unroll
    for (int jj = 0; jj < 4; jj++)
      #pragma unroll
      for (int tt = 0; tt < 8; tt++)
        acc[jj][tt] = fdot2u(wj[jj], xs[tt], acc[jj][tt]);
  }
  #pragma unroll
  for (int tt = 0; tt < 8; tt++){
    long T = T0 + 8*tg + tt;
    uint2 o;
    o.x = packh2(acc[0][tt], acc[1][tt]);
    o.y = packh2(acc[2][tt], acc[3][tt]);
    ((uint2*)scr)[T*64 + hg] = o;
  }
}

// ---------------- K3: recurrence. 512 thr: thread (i=tid>>4, j=tid&15) = 8 rows x 16 cols.
// Fold permutation baked into A-slot assignment: slot s holds row 8i + m(j ^ G(s)),
// G(s) = (s&3)|((s&4)<<1). Reduction: 7 dpp-adds + 1 swizzle dup, zero cndmask.
// h buffer: 16 col-blocks x 48 B stride (32 B data + 16 pad) -> b128 reads 2-way only.
// Measured: VALU-issue-bound at ~710 cyc/batch-step (r0+r3 counter fits agree);
// remaining ~390 cyc/step is lockstep barrier reconvergence (r9: not absorbable).
__global__ __launch_bounds__(512, 2) void k_recur(const void* __restrict__ A, const float* __restrict__ scale_p,
                                                  u32* __restrict__ scr, const int* __restrict__ flag){
  __shared__ alignas(16) char hbuf[2][768];
  __shared__ alignas(16) __half uring[32*256];    // 16 KB, 2 slots x 16 steps
  int tid = threadIdx.x;
  int i = tid >> 4, j = tid & 15;
  int b = blockIdx.x;
  int bf = *flag;
  float s = *scale_p;
  int myrow = 8*i + mloc(j);

  u32 a[8][8];
  #pragma unroll
  for (int sx = 0; sx < 8; sx++){
    int G = (sx & 3) | ((sx & 4) << 1);
    int R = 8*i + mloc(j ^ G);
    #pragma unroll
    for (int q = 0; q < 4; q++){
      float4 v = load4g(A, (long)R*64 + 4*j + q, bf);
      float vv[4] = {v.x, v.y, v.z, v.w};
      #pragma unroll
      for (int e = 0; e < 4; e++){
        int col = 16*j + 4*q + e;
        if (col == R) vv[e] = 0.f;
      }
      a[sx][2*q]   = packh2(vv[0]*s, vv[1]*s);
      a[sx][2*q+1] = packh2(vv[2]*s, vv[3]*s);
    }
  }
  float d = load1g(A, (long)myrow*257, bf) * s;   // diagonal of my final row, fp32

  const uint4* scr4 = (const uint4*)scr;
  uint4* ur4 = (uint4*)uring;
  long ubase4 = (long)b * 131072;                  // uint4 idx of u[b][0]
  u16* hsout = (u16*)scr + (long)b*4096*256;

  uint4 pf;
  ur4[tid] = scr4[ubase4 + tid];                   // chunk 0 -> slot 0
  pf = scr4[ubase4 + 512 + tid];                   // chunk 1 -> regs

  int hoff16 = 24*(myrow >> 4) + (myrow & 15);     // u16 idx: 48B block stride
  ((u16*)hbuf[0])[hoff16] = 0;
  ((u16*)hbuf[1])[hoff16] = 0;
  __syncthreads();

  float hprev = 0.f;
  #pragma unroll 1
  for (int t = 0; t < 4096; ++t){
    const uint4* h4 = (const uint4*)(hbuf[t & 1] + 48*j);
    uint4 h0 = h4[0], h1 = h4[1];
    float uv = __half2float(uring[(t & 31)*256 + myrow]);
    float acc[8];
    #pragma unroll
    for (int sx = 0; sx < 8; sx++){
      float ac = 0.f;
      ac = fdot2u(a[sx][0], h0.x, ac);
      ac = fdot2u(a[sx][1], h0.y, ac);
      ac = fdot2u(a[sx][2], h0.z, ac);
      ac = fdot2u(a[sx][3], h0.w, ac);
      ac = fdot2u(a[sx][4], h1.x, ac);
      ac = fdot2u(a[sx][5], h1.y, ac);
      ac = fdot2u(a[sx][6], h1.z, ac);
      ac = fdot2u(a[sx][7], h1.w, ac);
      acc[sx] = ac;
    }
    // fold bit0 (xor1), bit1 (xor2), bit2 (xor8); dup over xor4
    acc[0] += XOR1F(acc[1]);
    acc[2] += XOR1F(acc[3]);
    acc[4] += XOR1F(acc[5]);
    acc[6] += XOR1F(acc[7]);
    acc[0] += XOR2F(acc[2]);
    acc[4] += XOR2F(acc[6]);
    acc[0] += XOR8F(acc[4]);
    float sum = acc[0] + xor4f(acc[0]);

    float hnew = fmaxf(fmaf(d, hprev, sum + uv), 0.f);
    hprev = hnew;
    u16 hh = __half_as_ushort(__float2half(hnew));
    ((u16*)hbuf[(t & 1) ^ 1])[hoff16] = hh;        // dup lanes write same value
    hsout[(long)t*256 + myrow] = hh;               // dup lanes write same value

    if ((t & 15) == 15 && t < 4095){
      int ct = (t + 1) >> 4;
      ur4[(ct & 1)*512 + tid] = pf;
      if (ct < 255) pf = scr4[ubase4 + (long)(ct + 1)*512 + tid];
    }
    __syncthreads();
  }
}

// ---------------- K4: y = hs @ W_C^T ----------------
__global__ __launch_bounds__(256) void k_yproj(const u32* __restrict__ scr, const void* __restrict__ WC,
                                               void* __restrict__ y, const int* __restrict__ flag){
  __shared__ alignas(16) u32 Wt[128*132];
  __shared__ alignas(16) u32 ht[128*68];
  int tid = threadIdx.x, bf = *flag;
  long T0 = (long)blockIdx.x * 64;
  #pragma unroll
  for (int i2 = 0; i2 < 32; i2++){
    int f = tid + 256*i2;
    int kp = f & 127, t = f >> 7;
    ht[kp*68 + t] = scr[(T0 + t)*128 + kp];
  }
  #pragma unroll
  for (int i2 = 0; i2 < 32; i2++){
    int f = tid + 256*i2;
    int kq = f & 63, o = f >> 6;
    float4 v = load4g(WC, (long)o*64 + kq, bf);
    Wt[(2*kq)*132 + o]   = packh2(v.x, v.y);
    Wt[(2*kq+1)*132 + o] = packh2(v.z, v.w);
  }
  __syncthreads();
  int og = tid & 31, tg = tid >> 5;
  float acc[4][8];
  #pragma unroll
  for (int a1 = 0; a1 < 4; a1++)
    for (int b1 = 0; b1 < 8; b1++) acc[a1][b1] = 0.f;
  #pragma unroll 4
  for (int kp = 0; kp < 128; kp++){
    uint4 wv = *(const uint4*)&Wt[kp*132 + 4*og];
    uint4 ha = *(const uint4*)&ht[kp*68 + 8*tg];
    uint4 hc = *(const uint4*)&ht[kp*68 + 8*tg + 4];
    u32 wj[4] = {wv.x, wv.y, wv.z, wv.w};
    u32 hs8[8] = {ha.x, ha.y, ha.z, ha.w, hc.x, hc.y, hc.z, hc.w};
    #pragma unroll
    for (int jj = 0; jj < 4; jj++)
      #pragma unroll
      for (int tt = 0; tt < 8; tt++)
        acc[jj][tt] = fdot2u(wj[jj], hs8[tt], acc[jj][tt]);
  }
  #pragma unroll
  for (int tt = 0; tt < 8; tt++){
    long T = T0 + 8*tg + tt;
    if (!bf){
      float4 o = {acc[0][tt], acc[1][tt], acc[2][tt], acc[3][tt]};
      ((float4*)y)[T*32 + og] = o;
    } else {
      uint2 o;
      o.x = (u32)f2bf(acc[0][tt]) | ((u32)f2bf(acc[1][tt]) << 16);
      o.y = (u32)f2bf(acc[2][tt]) | ((u32)f2bf(acc[3][tt]) << 16);
      ((uint2*)y)[T*32 + og] = o;
    }
  }
}

extern "C" void kernel_launch(void* const* d_in, const int* in_sizes, int n_in,
                              void* d_out, int out_size, void* d_ws, size_t ws_size,
                              hipStream_t stream){
  const void* x  = d_in[0];
  const void* A  = d_in[1];
  const void* WB = d_in[2];
  const void* WC = d_in[3];

  float* Bm    = (float*)d_ws;
  float* scale = (float*)((char*)d_ws + 256*1024);
  int*   flag  = (int*)((char*)d_ws + 256*1024 + 64);

  const size_t scrOff = (size_t)1 << 20;
  const size_t scrBytes = (size_t)131072 * 256 * 2;   // 64 MiB of f16
  u32* scr = (ws_size >= scrOff + scrBytes + 4096)
               ? (u32*)((char*)d_ws + scrOff)
               : (u32*)d_out;

  k_detect <<<1, 1, 0, stream>>>(A, flag);
  k_btb    <<<256, 256, 0, stream>>>(A, Bm, flag);
  k_lanczos<<<1, 512, 0, stream>>>(Bm, scale);
  k_uproj  <<<4096, 256, 0, stream>>>(x, WB, scr, flag);
  k_recur  <<<32, 512, 0, stream>>>(A, scale, scr, flag);
  k_yproj  <<<2048, 256, 0, stream>>>(scr, WC, d_out, flag);
}